// Round 2
// baseline (242.347 us; speedup 1.0000x reference)
//
#include <hip/hip_runtime.h>

// QKV attention: qkv [B=64, 3*64, T=2048] fp32 -> out [64, 64, 2048] fp32.
// Round 9: SINGLE fused kernel (prep+gap was ~143us of the 239.8; gone).
//  - Q: per-block direct fp32 global loads -> scaled fp16 B-frags (prologue).
//  - K: per-tile fp32 LDS staging (swizzled) + cooperative transpose-convert
//    to fp16 Ks[s][c] (this is the old prep transpose, now in-loop).
//  - V: fp32 global -> pkrtz in registers at prefetch -> fp16 Vs[c][s].
//  - 32x32x16 MFMAs; S^T = K^T*Q so each lane owns full P columns; PV
//    B-frags rebuilt IN REGISTERS via 8x pkrtz + 4x v_permlane32_swap_b32
//    per 32x32 block (T12) -> P never touches LDS (was ~30% of LDS traffic).
//  - Wave owns 64 queries (BQ=256): halves LDS bytes/FLOP vs r8.
//  - 3 barriers/tile (stage / transpose / compute), one-tile-ahead reg
//    prefetch, s_setprio around MFMA clusters, bijective XCD swizzle
//    (8 query-blocks of one head -> same XCD for K/V L2 reuse).
// NOTE: v_cvt_pk_bf16_f32 inline asm proven wrong on HW (r3/4/5) - banned.

#define DHEAD 64
#define TLEN  2048
#define NB    64
#define BQ    256
#define BK    64
#define NT    (TLEN / BK)

typedef _Float16 h16x8 __attribute__((ext_vector_type(8)));
typedef _Float16 h16x2 __attribute__((ext_vector_type(2)));
typedef __fp16   fp16x2 __attribute__((ext_vector_type(2)));
typedef float    f32x16 __attribute__((ext_vector_type(16)));

// 1/sqrt(sqrt(64)) * sqrt(log2(e)): applied to Q and K; scores arrive
// pre-scaled for exp2.
#define QK_SCALE 0.42466090267246895f

extern "C" __device__ float __ocml_native_exp2_f32(float);

union H2U  { h16x2 h; fp16x2 f; unsigned u; };
union FRAG { h16x8 v; unsigned u[4]; };

__device__ __forceinline__ unsigned pk_u(float a, float b) {
    H2U x; x.f = __builtin_amdgcn_cvt_pkrtz(a, b); return x.u;   // v_cvt_pkrtz_f16_f32
}

// fp16 tile [row][64]: 8-elem (16B) granule XOR swizzle keyed on row&7.
__device__ __forceinline__ int swz(int row, int col) {
    return row * 64 + (col ^ ((row & 7) << 3));
}
// fp32 staging tile [c][64]: 4-elem (16B) granule XOR swizzle keyed on c>>3
// (keying on c&7 would be instruction-uniform in the transpose read ->
//  8-way conflict; c>>3 varies per lane -> 2-way = free).
__device__ __forceinline__ int swzf(int c, int s) {
    return c * 64 + (s ^ (((c >> 3) & 7) << 2));
}

__global__ __launch_bounds__(256, 2)
void attn(const float* __restrict__ qkv, float* __restrict__ out) {
    __shared__ alignas(16) float    Kst[64 * 64];   // fp32 K tile [c][s], swizzled
    __shared__ alignas(16) _Float16 Ks[64 * 64];    // fp16 K^T tile [s][c], swizzled, scaled
    __shared__ alignas(16) _Float16 Vs[64 * 64];    // fp16 V tile [c][s], swizzled

    const int tid  = threadIdx.x;
    const int wave = tid >> 6;
    const int lane = tid & 63;
    const int h    = lane >> 5;    // 32x32 MFMA half
    const int c32  = lane & 31;

    // bijective XCD swizzle: all 8 query-blocks of head b -> same XCD.
    const int flat = blockIdx.x + (int)gridDim.x * blockIdx.y;  // gridDim.x = 8
    const int j8   = flat & 7, m8 = flat >> 3;
    const int b    = ((m8 & 7) << 3) | j8;
    const int t0   = (m8 >> 3) * BQ + wave * 64;

    const float* qg = qkv + ((size_t)b * 3 + 0) * DHEAD * TLEN;
    const float* kg = qkv + ((size_t)b * 3 + 1) * DHEAD * TLEN;
    const float* vg = qkv + ((size_t)b * 3 + 2) * DHEAD * TLEN;

    // ---- hoist Q B-frags: B[k=c][n=t], lane (h,c32) holds Q[t0+nb*32+c32][kb*16+h*8+j]
    h16x8 qf[2][4];
    #pragma unroll
    for (int nb = 0; nb < 2; ++nb)
        #pragma unroll
        for (int kb = 0; kb < 4; ++kb) {
            const float* qp = qg + (size_t)(kb * 16 + h * 8) * TLEN + t0 + nb * 32 + c32;
            FRAG f;
            #pragma unroll
            for (int w = 0; w < 4; ++w)
                f.u[w] = pk_u(qp[(size_t)(2 * w) * TLEN] * QK_SCALE,
                              qp[(size_t)(2 * w + 1) * TLEN] * QK_SCALE);
            qf[nb][kb] = f.v;
        }

    f32x16 acco[2][2];
    #pragma unroll
    for (int cb = 0; cb < 2; ++cb)
        #pragma unroll
        for (int nb = 0; nb < 2; ++nb)
            #pragma unroll
            for (int r = 0; r < 16; ++r) acco[cb][nb][r] = 0.f;
    float lp[2] = {0.f, 0.f};

    // staging map: thread -> (c row, 16-wide s chunk)
    const int sc = tid >> 2;
    const int sq = (tid & 3) * 16;
    // transpose map: thread -> (s row pair, 8-wide c chunk)
    const int ts_s   = tid >> 3;          // s and s+32
    const int ts_c   = (tid & 7) * 8;     // c base (c>>3 == tid&7 for all 8 c's)
    const int ts_key = (tid & 7) << 2;    // matching fp32 swizzle key

    float4 kc[4];
    h16x8  vc2[2];

    auto PREF = [&](int s0) {
        const float* kp = kg + (size_t)sc * TLEN + s0 + sq;
        const float* vp = vg + (size_t)sc * TLEN + s0 + sq;
        #pragma unroll
        for (int k = 0; k < 4; ++k) kc[k] = *(const float4*)(kp + 4 * k);
        float4 v0 = *(const float4*)(vp + 0);
        float4 v1 = *(const float4*)(vp + 4);
        float4 v2 = *(const float4*)(vp + 8);
        float4 v3 = *(const float4*)(vp + 12);
        FRAG a, c;
        a.u[0] = pk_u(v0.x, v0.y); a.u[1] = pk_u(v0.z, v0.w);
        a.u[2] = pk_u(v1.x, v1.y); a.u[3] = pk_u(v1.z, v1.w);
        c.u[0] = pk_u(v2.x, v2.y); c.u[1] = pk_u(v2.z, v2.w);
        c.u[2] = pk_u(v3.x, v3.y); c.u[3] = pk_u(v3.z, v3.w);
        vc2[0] = a.v; vc2[1] = c.v;
    };

    PREF(0);

    for (int it = 0; it < NT; ++it) {
        __syncthreads();                       // (1) prior tile frag-reads done
        #pragma unroll
        for (int k = 0; k < 4; ++k)
            *(float4*)&Kst[swzf(sc, sq + 4 * k)] = kc[k];
        *(h16x8*)&Vs[swz(sc, sq)]     = vc2[0];
        *(h16x8*)&Vs[swz(sc, sq + 8)] = vc2[1];
        __syncthreads();                       // (2) staging visible

        if (it + 1 < NT) PREF((it + 1) * BK);  // in flight across transpose+compute

        // cooperative transpose-convert: Kst[c][s] fp32 -> Ks[s][c] fp16 * scale
        #pragma unroll
        for (int half = 0; half < 2; ++half) {
            const int s    = ts_s + half * 32;
            const int scol = s ^ ts_key;
            FRAG f;
            #pragma unroll
            for (int w = 0; w < 4; ++w) {
                float f0 = Kst[(ts_c + 2 * w) * 64 + scol];
                float f1 = Kst[(ts_c + 2 * w + 1) * 64 + scol];
                f.u[w] = pk_u(f0 * QK_SCALE, f1 * QK_SCALE);
            }
            *(h16x8*)&Ks[swz(s, ts_c)] = f.v;
        }
        __syncthreads();                       // (3) Ks ready

        #pragma unroll
        for (int mb = 0; mb < 2; ++mb) {
            // ---- S^T = K^T Q : D[m=s][n=t], lane holds rows (r&3)+8*(r>>2)+4h
            f32x16 accs[2];
            #pragma unroll
            for (int nb = 0; nb < 2; ++nb)
                #pragma unroll
                for (int r = 0; r < 16; ++r) accs[nb][r] = 0.f;

            __builtin_amdgcn_s_setprio(1);
            #pragma unroll
            for (int kb = 0; kb < 4; ++kb) {
                h16x8 ka = *(const h16x8*)&Ks[swz(mb * 32 + c32, kb * 16 + h * 8)];
                accs[0] = __builtin_amdgcn_mfma_f32_32x32x16_f16(ka, qf[0][kb], accs[0], 0, 0, 0);
                accs[1] = __builtin_amdgcn_mfma_f32_32x32x16_f16(ka, qf[1][kb], accs[1], 0, 0, 0);
            }
            __builtin_amdgcn_s_setprio(0);

            // ---- softmax numerator (exp2, scale pre-folded) + in-register
            // B-frag rebuild: regs (e0..e7)->s_loc 0..15, (e8..e15)->16..31.
            // w0=(a01'),w1=(a23'),w2=(b01'),w3=(b23') after permlane32_swap.
            h16x8 pb[2][2];   // [kb16][nb]
            #pragma unroll
            for (int nb = 0; nb < 2; ++nb) {
                float e[16];
                #pragma unroll
                for (int r = 0; r < 16; ++r) e[r] = __ocml_native_exp2_f32(accs[nb][r]);
                float s0 = 0.f;
                #pragma unroll
                for (int r = 0; r < 16; ++r) s0 += e[r];
                lp[nb] += s0;
                #pragma unroll
                for (int kb16 = 0; kb16 < 2; ++kb16) {
                    const float* ee = e + kb16 * 8;
                    unsigned a01 = pk_u(ee[0], ee[1]);
                    unsigned a23 = pk_u(ee[2], ee[3]);
                    unsigned b01 = pk_u(ee[4], ee[5]);
                    unsigned b23 = pk_u(ee[6], ee[7]);
                    asm volatile("v_permlane32_swap_b32 %0, %1" : "+v"(a01), "+v"(b01));
                    asm volatile("v_permlane32_swap_b32 %0, %1" : "+v"(a23), "+v"(b23));
                    FRAG f;
                    f.u[0] = a01; f.u[1] = a23; f.u[2] = b01; f.u[3] = b23;
                    pb[kb16][nb] = f.v;
                }
            }

            // ---- O^T += V P^T : A = Vs rows, B = pb (registers, no LDS)
            __builtin_amdgcn_s_setprio(1);
            #pragma unroll
            for (int kb16 = 0; kb16 < 2; ++kb16) {
                const int scol = mb * 32 + kb16 * 16 + h * 8;
                #pragma unroll
                for (int cb = 0; cb < 2; ++cb) {
                    h16x8 va = *(const h16x8*)&Vs[swz(cb * 32 + c32, scol)];
                    acco[cb][0] = __builtin_amdgcn_mfma_f32_32x32x16_f16(va, pb[kb16][0], acco[cb][0], 0, 0, 0);
                    acco[cb][1] = __builtin_amdgcn_mfma_f32_32x32x16_f16(va, pb[kb16][1], acco[cb][1], 0, 0, 0);
                }
            }
            __builtin_amdgcn_s_setprio(0);
        }
    }

    // ---- finalize: lane h and h^1 (xor 32) hold complementary s-rows
    float rinv[2];
    #pragma unroll
    for (int nb = 0; nb < 2; ++nb) {
        float l = lp[nb];
        l += __shfl_xor(l, 32);
        rinv[nb] = 1.0f / l;
    }

    float* ob = out + (size_t)b * DHEAD * TLEN + t0;
    #pragma unroll
    for (int cb = 0; cb < 2; ++cb)
        #pragma unroll
        for (int nb = 0; nb < 2; ++nb)
            #pragma unroll
            for (int r = 0; r < 16; ++r) {
                const int c = cb * 32 + (r & 3) + 8 * (r >> 2) + 4 * h;
                ob[(size_t)c * TLEN + nb * 32 + c32] = acco[cb][nb][r] * rinv[nb];
            }
}

extern "C" void kernel_launch(void* const* d_in, const int* in_sizes, int n_in,
                              void* d_out, int out_size, void* d_ws, size_t ws_size,
                              hipStream_t stream) {
    const float* qkv = (const float*)d_in[0];
    float* out = (float*)d_out;
    attn<<<dim3(TLEN / BQ, NB), 256, 0, stream>>>(qkv, out);
}

// Round 3
// 219.895 us; speedup vs baseline: 1.1021x; 1.1021x over previous
//
#include <hip/hip_runtime.h>

// QKV attention: qkv [B=64, 3*64, T=2048] fp32 -> out [64, 64, 2048] fp32.
// Round 10: recombination of proven pieces after r9 post-mortem.
//  - ~100us of dur_us is fixed harness overhead (calibrated r9: single 142us
//    kernel -> 242us total). Objective = minimize GPU kernel time.
//  - prep_k: r8's LDS transpose-convert, K ONLY (Q loads direct in attn
//    prologue; V converts in-register during attn staging). ~10us.
//  - attn: r9's verified compute core (32x32 MFMA, S^T layout, in-register
//    softmax via exp2 + pkrtz + v_permlane32_swap_b32 -> P never in LDS)
//    with the in-loop transpose / fp32 Kst / 3rd barrier DELETED. K stages
//    from pre-transposed fp16 ws exactly like V. 2-barrier r8 skeleton,
//    one-tile-ahead register prefetch, LDS 16KB/block, BQ=256.
//  - r9's fp32 staging-write conflicts (256B rows -> all rows start bank 0,
//    ~4-way) are gone with Kst; all remaining LDS patterns derived 8/bank
//    (b128 minimum) or 2-way.
// NOTE: v_cvt_pk_bf16_f32 inline asm proven wrong on HW (r3/4/5) - banned.

#define DHEAD 64
#define TLEN  2048
#define NB    64
#define BQ    256
#define BK    64
#define NT    (TLEN / BK)
#define LDT   65      // prep fp32 transpose leading dim

typedef _Float16 h16x8 __attribute__((ext_vector_type(8)));
typedef _Float16 h16x2 __attribute__((ext_vector_type(2)));
typedef __fp16   fp16x2 __attribute__((ext_vector_type(2)));
typedef float    f32x16 __attribute__((ext_vector_type(16)));

// 1/sqrt(sqrt(64)) * sqrt(log2(e)): applied to Q and K; scores arrive
// pre-scaled for exp2.
#define QK_SCALE 0.42466090267246895f

extern "C" __device__ float __ocml_native_exp2_f32(float);

union H2U  { h16x2 h; fp16x2 f; unsigned u; };
union FRAG { h16x8 v; unsigned u[4]; };

__device__ __forceinline__ unsigned pk_u(float a, float b) {
    H2U x; x.f = __builtin_amdgcn_cvt_pkrtz(a, b); return x.u;   // v_cvt_pkrtz_f16_f32
}

// fp16 tile [row][64]: 8-elem (16B) granule XOR swizzle keyed on row&7.
__device__ __forceinline__ int swz(int row, int col) {
    return row * 64 + (col ^ ((row & 7) << 3));
}

// ---------- prep: K -> fp16 [b][s][c] (transposed, pre-scaled) ----------
__global__ __launch_bounds__(256)
void prep_k(const float* __restrict__ qkv, _Float16* __restrict__ ws) {
    __shared__ float T32[64 * LDT];
    const int tile = blockIdx.x, b = blockIdx.y;
    const int tid = threadIdx.x;
    const float* src = qkv + ((size_t)b * 3 + 1) * DHEAD * TLEN + tile * 64;
    _Float16* dst = ws + (size_t)b * DHEAD * TLEN + (size_t)tile * 64 * DHEAD;
    {
        int c = tid >> 4, t4 = (tid & 15) * 4;
        #pragma unroll
        for (int rr = 0; rr < 4; ++rr, c += 16) {
            float4 f = *(const float4*)(src + c * TLEN + t4);
            T32[(t4 + 0) * LDT + c] = f.x;
            T32[(t4 + 1) * LDT + c] = f.y;
            T32[(t4 + 2) * LDT + c] = f.z;
            T32[(t4 + 3) * LDT + c] = f.w;
        }
    }
    __syncthreads();
    #pragma unroll
    for (int rep = 0; rep < 2; ++rep) {
        int idx = rep * 256 + tid;
        int t = idx >> 3, j = idx & 7;
        const float* row = &T32[t * LDT + j * 8];
        FRAG o;
        o.u[0] = pk_u(row[0] * QK_SCALE, row[1] * QK_SCALE);
        o.u[1] = pk_u(row[2] * QK_SCALE, row[3] * QK_SCALE);
        o.u[2] = pk_u(row[4] * QK_SCALE, row[5] * QK_SCALE);
        o.u[3] = pk_u(row[6] * QK_SCALE, row[7] * QK_SCALE);
        *(h16x8*)(dst + t * DHEAD + j * 8) = o.v;
    }
}

// ---------- attention ----------
__global__ __launch_bounds__(256, 2)
void attn(const float* __restrict__ qkv, const _Float16* __restrict__ kt,
          float* __restrict__ out) {
    __shared__ alignas(16) _Float16 Ks[64 * 64];    // fp16 K^T tile [s][c], swizzled, scaled
    __shared__ alignas(16) _Float16 Vs[64 * 64];    // fp16 V tile [c][s], swizzled

    const int tid  = threadIdx.x;
    const int wave = tid >> 6;
    const int lane = tid & 63;
    const int h    = lane >> 5;    // 32x32 MFMA half
    const int c32  = lane & 31;

    // bijective XCD swizzle: all 8 query-blocks of head b -> XCD (b&7).
    const int flat = blockIdx.x + (int)gridDim.x * blockIdx.y;  // gridDim.x = 8
    const int j8   = flat & 7, m8 = flat >> 3;
    const int b    = ((m8 & 7) << 3) | j8;
    const int t0   = (m8 >> 3) * BQ + wave * 64;

    const float* qg = qkv + ((size_t)b * 3 + 0) * DHEAD * TLEN;
    const float* vg = qkv + ((size_t)b * 3 + 2) * DHEAD * TLEN;
    const _Float16* kb = kt + (size_t)b * DHEAD * TLEN;

    // ---- hoist Q B-frags: B[k=c][n=t], lane (h,c32) holds Q[t0+nb*32+c32][kb*16+h*8+j]
    h16x8 qf[2][4];
    #pragma unroll
    for (int nb = 0; nb < 2; ++nb)
        #pragma unroll
        for (int kbq = 0; kbq < 4; ++kbq) {
            const float* qp = qg + (size_t)(kbq * 16 + h * 8) * TLEN + t0 + nb * 32 + c32;
            FRAG f;
            #pragma unroll
            for (int w = 0; w < 4; ++w)
                f.u[w] = pk_u(qp[(size_t)(2 * w) * TLEN] * QK_SCALE,
                              qp[(size_t)(2 * w + 1) * TLEN] * QK_SCALE);
            qf[nb][kbq] = f.v;
        }

    f32x16 acco[2][2];
    #pragma unroll
    for (int cb = 0; cb < 2; ++cb)
        #pragma unroll
        for (int nb = 0; nb < 2; ++nb)
            #pragma unroll
            for (int r = 0; r < 16; ++r) acco[cb][nb][r] = 0.f;
    float lp[2] = {0.f, 0.f};

    // staging map: thread -> (row, 16-elem chunk). Same map for Ks and Vs.
    const int sr = tid >> 2;           // Ks: s row   | Vs: c row
    const int sq = (tid & 3) * 16;     // chunk base

    h16x8 kc2[2], vc2[2];

    auto PREF = [&](int s0) {
        const _Float16* kp = kb + (size_t)(s0 + sr) * DHEAD + sq;
        kc2[0] = *(const h16x8*)(kp);
        kc2[1] = *(const h16x8*)(kp + 8);
        const float* vp = vg + (size_t)sr * TLEN + s0 + sq;
        float4 v0 = *(const float4*)(vp + 0);
        float4 v1 = *(const float4*)(vp + 4);
        float4 v2 = *(const float4*)(vp + 8);
        float4 v3 = *(const float4*)(vp + 12);
        FRAG a, c;
        a.u[0] = pk_u(v0.x, v0.y); a.u[1] = pk_u(v0.z, v0.w);
        a.u[2] = pk_u(v1.x, v1.y); a.u[3] = pk_u(v1.z, v1.w);
        c.u[0] = pk_u(v2.x, v2.y); c.u[1] = pk_u(v2.z, v2.w);
        c.u[2] = pk_u(v3.x, v3.y); c.u[3] = pk_u(v3.z, v3.w);
        vc2[0] = a.v; vc2[1] = c.v;
    };

    PREF(0);

    for (int it = 0; it < NT; ++it) {
        __syncthreads();                       // (1) prior tile frag-reads done
        *(h16x8*)&Ks[swz(sr, sq)]     = kc2[0];
        *(h16x8*)&Ks[swz(sr, sq + 8)] = kc2[1];
        *(h16x8*)&Vs[swz(sr, sq)]     = vc2[0];
        *(h16x8*)&Vs[swz(sr, sq + 8)] = vc2[1];
        __syncthreads();                       // (2) staging visible

        if (it + 1 < NT) PREF((it + 1) * BK);  // in flight across compute

        #pragma unroll
        for (int mb = 0; mb < 2; ++mb) {
            // ---- S^T = K^T Q : D[m=s][n=t], lane holds rows (r&3)+8*(r>>2)+4h
            f32x16 accs[2];
            #pragma unroll
            for (int nb = 0; nb < 2; ++nb)
                #pragma unroll
                for (int r = 0; r < 16; ++r) accs[nb][r] = 0.f;

            __builtin_amdgcn_s_setprio(1);
            #pragma unroll
            for (int kbq = 0; kbq < 4; ++kbq) {
                h16x8 ka = *(const h16x8*)&Ks[swz(mb * 32 + c32, kbq * 16 + h * 8)];
                accs[0] = __builtin_amdgcn_mfma_f32_32x32x16_f16(ka, qf[0][kbq], accs[0], 0, 0, 0);
                accs[1] = __builtin_amdgcn_mfma_f32_32x32x16_f16(ka, qf[1][kbq], accs[1], 0, 0, 0);
            }
            __builtin_amdgcn_s_setprio(0);

            // ---- softmax numerator (exp2, scale pre-folded) + in-register
            // B-frag rebuild: 8x pkrtz + 4x permlane32_swap per 32x32 block.
            h16x8 pb[2][2];   // [kb16][nb]
            #pragma unroll
            for (int nb = 0; nb < 2; ++nb) {
                float e[16];
                #pragma unroll
                for (int r = 0; r < 16; ++r) e[r] = __ocml_native_exp2_f32(accs[nb][r]);
                float s0 = 0.f;
                #pragma unroll
                for (int r = 0; r < 16; ++r) s0 += e[r];
                lp[nb] += s0;
                #pragma unroll
                for (int kb16 = 0; kb16 < 2; ++kb16) {
                    const float* ee = e + kb16 * 8;
                    unsigned a01 = pk_u(ee[0], ee[1]);
                    unsigned a23 = pk_u(ee[2], ee[3]);
                    unsigned b01 = pk_u(ee[4], ee[5]);
                    unsigned b23 = pk_u(ee[6], ee[7]);
                    asm volatile("v_permlane32_swap_b32 %0, %1" : "+v"(a01), "+v"(b01));
                    asm volatile("v_permlane32_swap_b32 %0, %1" : "+v"(a23), "+v"(b23));
                    FRAG f;
                    f.u[0] = a01; f.u[1] = a23; f.u[2] = b01; f.u[3] = b23;
                    pb[kb16][nb] = f.v;
                }
            }

            // ---- O^T += V P^T : A = Vs rows, B = pb (registers, no LDS)
            __builtin_amdgcn_s_setprio(1);
            #pragma unroll
            for (int kb16 = 0; kb16 < 2; ++kb16) {
                const int scol = mb * 32 + kb16 * 16 + h * 8;
                #pragma unroll
                for (int cb = 0; cb < 2; ++cb) {
                    h16x8 va = *(const h16x8*)&Vs[swz(cb * 32 + c32, scol)];
                    acco[cb][0] = __builtin_amdgcn_mfma_f32_32x32x16_f16(va, pb[kb16][0], acco[cb][0], 0, 0, 0);
                    acco[cb][1] = __builtin_amdgcn_mfma_f32_32x32x16_f16(va, pb[kb16][1], acco[cb][1], 0, 0, 0);
                }
            }
            __builtin_amdgcn_s_setprio(0);
        }
    }

    // ---- finalize: lane h and h^1 (xor 32) hold complementary s-rows
    float rinv[2];
    #pragma unroll
    for (int nb = 0; nb < 2; ++nb) {
        float l = lp[nb];
        l += __shfl_xor(l, 32);
        rinv[nb] = 1.0f / l;
    }

    float* ob = out + (size_t)b * DHEAD * TLEN + t0;
    #pragma unroll
    for (int cb = 0; cb < 2; ++cb)
        #pragma unroll
        for (int nb = 0; nb < 2; ++nb)
            #pragma unroll
            for (int r = 0; r < 16; ++r) {
                const int c = cb * 32 + (r & 3) + 8 * (r >> 2) + 4 * h;
                ob[(size_t)c * TLEN + nb * 32 + c32] = acco[cb][nb][r] * rinv[nb];
            }
}

extern "C" void kernel_launch(void* const* d_in, const int* in_sizes, int n_in,
                              void* d_out, int out_size, void* d_ws, size_t ws_size,
                              hipStream_t stream) {
    const float* qkv = (const float*)d_in[0];
    _Float16* ws = (_Float16*)d_ws;   // Kt: 64*64*2048*2 B = 16.8 MB
    float* out = (float*)d_out;
    prep_k<<<dim3(TLEN / 64, NB), 256, 0, stream>>>(qkv, ws);
    attn<<<dim3(TLEN / BQ, NB), 256, 0, stream>>>(qkv, ws, out);
}